// Round 13
// baseline (500.646 us; speedup 1.0000x reference)
//
#include <hip/hip_runtime.h>
#include <stdint.h>

#define BATCH 16
#define CIN   32
#define HH    128
#define WW    128
#define BO    32
#define OCH   128   // 4*BO
#define DEPTH 64

// ws layout (kept compatible with fallback): [0,4096) progress; [4096,+RINGMAX)
// ring (fallback only); [4096+RINGMAX, +I2SHSZ) i2s f16 [b][t][row][o]
#define RINGMAX ((size_t)BATCH * 16 * DEPTH * BO * 8)
#define I2SHSZ  ((size_t)BATCH * WW * HH * OCH * 2)

typedef _Float16 f16x4v __attribute__((ext_vector_type(4)));
typedef _Float16 f16x8v __attribute__((ext_vector_type(8)));
typedef float    f32x4v __attribute__((ext_vector_type(4)));

// ===== K1: i2s_h[b][t][row][o] = (f16)(b2+b1 + sum_c W2[o][c]*xskew) ========
__global__ __launch_bounds__(256, 4) void i2s_gemm_h(
    const float* __restrict__ x, const float* __restrict__ W2g,
    const float* __restrict__ b2, const float* __restrict__ b1,
    _Float16* __restrict__ i2sh)
{
    const int tid = threadIdx.x;
    const int bx  = blockIdx.x;
    const int b   = bx >> 7;
    const int row = bx & 127;

    __shared__ __attribute__((aligned(16))) float xs[CIN][WW];
    __shared__ __attribute__((aligned(16))) float w2s[CIN][OCH];
    __shared__ float bs[OCH];

    for (int i = tid; i < CIN * OCH; i += 256) {
        const int c = i >> 7, o = i & 127;
        w2s[c][o] = W2g[o * CIN + c];
    }
    if (tid < OCH) bs[tid] = b2[tid] + b1[tid];
    for (int i = tid; i < CIN * WW; i += 256) {
        const int c = i >> 7, t = i & 127;
        xs[c][t] = (t >= row)
            ? x[((size_t)(b * CIN + c) * HH + row) * WW + (t - row)] : 0.f;
    }
    __syncthreads();

    const int tm = tid >> 4;
    const int tn = tid & 15;
    const int t0 = tm * 8, o0 = tn * 8;

    float bv[8];
    *(float4*)&bv[0] = *(const float4*)&bs[o0];
    *(float4*)&bv[4] = *(const float4*)&bs[o0 + 4];
    float acc[8][8];
#pragma unroll
    for (int i = 0; i < 8; ++i)
#pragma unroll
        for (int jj = 0; jj < 8; ++jj) acc[i][jj] = bv[jj];

    for (int c = 0; c < CIN; ++c) {
        float a[8], wv[8];
        *(float4*)&a[0]  = *(const float4*)&xs[c][t0];
        *(float4*)&a[4]  = *(const float4*)&xs[c][t0 + 4];
        *(float4*)&wv[0] = *(const float4*)&w2s[c][o0];
        *(float4*)&wv[4] = *(const float4*)&w2s[c][o0 + 4];
#pragma unroll
        for (int i = 0; i < 8; ++i)
#pragma unroll
            for (int jj = 0; jj < 8; ++jj)
                acc[i][jj] = fmaf(a[i], wv[jj], acc[i][jj]);
    }

#pragma unroll
    for (int i = 0; i < 8; ++i) {
        f16x8v hv;
#pragma unroll
        for (int jj = 0; jj < 8; ++jj) hv[jj] = (_Float16)acc[i][jj];
        *(f16x8v*)&i2sh[((size_t)(b * WW + (t0 + i)) * HH + row) * OCH + o0] = hv;
    }
}

// ===== K2 v13: ONE BLOCK PER BATCH IMAGE — barrier-only scan.
// Key realization: step t depends ONLY on step t-1's h (the h-1 shift is also
// previous-step). Rows are fully parallel within a step -> the cross-block
// ring/atomic machinery of R1-R12 was unnecessary and its L2 latency was the
// bottleneck. 16 waves: wave (m,p) = M-tile m (rows 16m..16m+15) x N-tiles
// {p,p+2,p+4,p+6}; 8 MFMAs/wave, bw=32 VGPRs (v12-proven numerics/layouts);
// cells register-local; ONE __syncthreads per step.
__global__ __launch_bounds__(1024, 4) void diag_lstm_scan_v13(
    const float* __restrict__ W1g, float* __restrict__ out,
    const _Float16* __restrict__ i2sh)
{
    const int tid = threadIdx.x;
    const int l   = tid & 63;
    const int w   = tid >> 6;       // wave 0..15
    const int m   = w >> 1;         // M-tile 0..7
    const int p   = w & 1;          // N-parity
    const int q   = l >> 4;         // 0..3
    const int col = l & 15;
    const int b   = blockIdx.x;     // 0..15

    // phs[par][LDS row = global row + 1][ch]; row 0 = zero boundary. pad 44:
    // A-read bank step = 22 words/row -> 16 rows cover 16 distinct banks.
    __shared__ _Float16 phs[2][HH + 1][44];
    for (int i = tid; i < 2 * (HH + 1) * 44; i += 1024)
        (&phs[0][0][0])[i] = (_Float16)0.f;

    // ---- B-frags (loaded once): bw[s][h]; N-tile nt=p+2s;
    //      B[n=col][kk=8q+e] = W1[o=16nt+col][32h+8q+e]
    f16x8v bw[4][2];
#pragma unroll
    for (int s = 0; s < 4; ++s) {
        const int o = (p + 2 * s) * 16 + col;
#pragma unroll
        for (int h = 0; h < 2; ++h) {
            const float4 w0 = *(const float4*)&W1g[(size_t)o * 64 + 32 * h + 8 * q];
            const float4 w1 = *(const float4*)&W1g[(size_t)o * 64 + 32 * h + 8 * q + 4];
            f16x8v v;
            v[0] = (_Float16)w0.x; v[1] = (_Float16)w0.y;
            v[2] = (_Float16)w0.z; v[3] = (_Float16)w0.w;
            v[4] = (_Float16)w1.x; v[5] = (_Float16)w1.y;
            v[6] = (_Float16)w1.z; v[7] = (_Float16)w1.w;
            bw[s][h] = v;
        }
    }

    // ---- i2s per-lane prefetch (1-deep): row grow0+e, channel j+32s ----
    const ushort* i2su = (const ushort*)i2sh;
    const int j = 16 * p + col;
    const int grow0 = 16 * m + 4 * q;
    ushort u[4][4];
    {
        const size_t base = ((size_t)(b * WW + 0) * HH + grow0) * OCH + j;
#pragma unroll
        for (int s = 0; s < 4; ++s)
#pragma unroll
            for (int e = 0; e < 4; ++e)
                u[s][e] = i2su[base + (size_t)e * OCH + 32 * s];
    }

    float pc[4] = {0.f, 0.f, 0.f, 0.f};

    __syncthreads();

    for (int t = 0; t < WW; ++t) {
        _Float16 (*PS)[44] = phs[t & 1];
        _Float16 (*PD)[44] = phs[(t & 1) ^ 1];

        // ---- A-frags (v11/v12-verified layout) ----
        const f16x4v r0 = *(const f16x4v*)&PS[16 * m + col][4 * q];
        const f16x4v r1 = *(const f16x4v*)&PS[16 * m + col + 1][4 * q];
        const f16x4v r2 = *(const f16x4v*)&PS[16 * m + col][16 + 4 * q];
        const f16x4v r3 = *(const f16x4v*)&PS[16 * m + col + 1][16 + 4 * q];
        f16x8v af0, af1;
        af0[0] = r0[0]; af0[1] = r1[0]; af0[2] = r0[1]; af0[3] = r1[1];
        af0[4] = r0[2]; af0[5] = r1[2]; af0[6] = r0[3]; af0[7] = r1[3];
        af1[0] = r2[0]; af1[1] = r3[0]; af1[2] = r2[1]; af1[3] = r3[1];
        af1[4] = r2[2]; af1[5] = r3[2]; af1[6] = r2[3]; af1[7] = r3[3];

        // ---- acc init from i2s prefetch; refill for t+1 ----
        f32x4v acc[4];
#pragma unroll
        for (int s = 0; s < 4; ++s)
#pragma unroll
            for (int e = 0; e < 4; ++e) {
                ushort uv = u[s][e];
                acc[s][e] = (float)(*reinterpret_cast<const _Float16*>(&uv));
            }
        {
            const int tn = (t + 1 < WW) ? t + 1 : WW - 1;
            const size_t base = ((size_t)(b * WW + tn) * HH + grow0) * OCH + j;
#pragma unroll
            for (int s = 0; s < 4; ++s)
#pragma unroll
                for (int e = 0; e < 4; ++e)
                    u[s][e] = i2su[base + (size_t)e * OCH + 32 * s];
        }

        // ---- 8 MFMAs: gates = W1 · [h_prev_row; h_cur_row] + i2s ----
#pragma unroll
        for (int s = 0; s < 4; ++s) {
            acc[s] = __builtin_amdgcn_mfma_f32_16x16x32_f16(af0, bw[s][0], acc[s], 0, 0, 0);
            acc[s] = __builtin_amdgcn_mfma_f32_16x16x32_f16(af1, bw[s][1], acc[s], 0, 0, 0);
        }

        // ---- cells: 4/lane, register-local ----
#pragma unroll
        for (int e = 0; e < 4; ++e) {
            const float go = acc[0][e];
            const float gf = acc[1][e];
            const float gi = acc[2][e];
            const float gg = acc[3][e];
            const float so = 1.f / (1.f + __expf(-go));
            const float sf = 1.f / (1.f + __expf(-gf));
            const float si = 1.f / (1.f + __expf(-gi));
            const float tg = 2.f / (1.f + __expf(-2.f * gg)) - 1.f;
            const float nc = sf * pc[e] + si * tg;
            const float th = 2.f / (1.f + __expf(-2.f * nc)) - 1.f;
            const float nh = so * th;
            pc[e] = nc;
            PD[grow0 + e + 1][j] = (_Float16)nh;
            out[((size_t)(b * BO + j) * HH + (grow0 + e)) * WW + t] = nh;
        }

        __syncthreads();   // publish PD for next step
    }
}

// ===================== fallback (R4, proven, ws-lean) =====================
__global__ __launch_bounds__(512, 2) void diag_lstm_scan_v4(
    const float* __restrict__ x, const float* __restrict__ W2g,
    const float* __restrict__ b2, const float* __restrict__ W1g,
    const float* __restrict__ b1, float* __restrict__ out,
    int* __restrict__ progress, unsigned long long* __restrict__ hand)
{
    const int tid = threadIdx.x;
    const int l   = tid & 63;
    const int w   = tid >> 6;
    const int blk = blockIdx.x;
    const int b = (blk & 7) + ((blk >> 7) << 3);
    const int k = (blk >> 3) & 15;
    const int row = k * 8 + w;

    __shared__ __attribute__((aligned(16))) float phs[2][9][BO];
    __shared__ __attribute__((aligned(16))) float xbuf[8][CIN];
    __shared__ __attribute__((aligned(16))) float gbuf2[8][OCH];

    for (int i = tid; i < 2 * 9 * BO; i += 512) ((float*)phs)[i] = 0.f;

    const int o0 = 2 * l, o1 = 2 * l + 1;
    float w2a[CIN], w2b[CIN], w1pa[CIN], w1ca[CIN], w1pb[CIN], w1cb[CIN];
#pragma unroll
    for (int c = 0; c < CIN; ++c) {
        w2a[c]  = W2g[o0 * CIN + c];
        w2b[c]  = W2g[o1 * CIN + c];
        w1pa[c] = W1g[(o0 * CIN + c) * 2 + 0];
        w1ca[c] = W1g[(o0 * CIN + c) * 2 + 1];
        w1pb[c] = W1g[(o1 * CIN + c) * 2 + 0];
        w1cb[c] = W1g[(o1 * CIN + c) * 2 + 1];
    }
    const float biasA = b2[o0] + b1[o0];
    const float biasB = b2[o1] + b1[o1];

    const int j = l & 31;
    float pc = 0.f, ob0 = 0.f, ob1 = 0.f, ob2 = 0.f;
    float* outrow = out + ((size_t)(b * BO + j) * HH + row) * WW;

    const int kprev = (k > 0) ? k - 1 : 0;
    const unsigned long long* srcbase =
        hand + (size_t)((b * 16 + kprev) * DEPTH) * BO + j;
    unsigned long long* dstbase =
        hand + (size_t)((b * 16 + k) * DEPTH) * BO + j;
    int* myprog   = progress + (b * 16 + k);
    int* consprog = myprog + 1;

    unsigned long long pre = 0ull;
    __syncthreads();

    for (int t = 0; t < WW; ++t) {
        const int par = t & 1;
        if (l < 32) {
            const int wp = t - row;
            xbuf[w][l] = (wp >= 0)
                ? x[((size_t)(b * CIN + l) * HH + row) * WW + wp] : 0.f;
        }
        if (w == 0 && k > 0) {
            if (t > 0) {
                unsigned long long q = pre;
                while (__any((unsigned)(q >> 32) != (unsigned)t)) {
                    q = __hip_atomic_load(&srcbase[(size_t)((t - 1) & (DEPTH - 1)) * BO],
                                          __ATOMIC_RELAXED, __HIP_MEMORY_SCOPE_AGENT);
                }
                if (l < 32) phs[par][0][l] = __uint_as_float((unsigned)q);
            }
            pre = __hip_atomic_load(&srcbase[(size_t)(t & (DEPTH - 1)) * BO],
                                    __ATOMIC_RELAXED, __HIP_MEMORY_SCOPE_AGENT);
        }
        asm volatile("s_waitcnt lgkmcnt(0)" ::: "memory");

        float ga = biasA, gb = biasB;
        {
            const float4* xb4 = (const float4*)(&xbuf[w][0]);
            const float4* pv4 = (const float4*)(&phs[par][w][0]);
            const float4* qv4 = (const float4*)(&phs[par][w + 1][0]);
#pragma unroll
            for (int cc = 0; cc < CIN / 4; ++cc) {
                const float4 xv = xb4[cc];
                const float4 pv = pv4[cc];
                const float4 qv = qv4[cc];
                const float* xs = (const float*)&xv;
                const float* ps = (const float*)&pv;
                const float* qs = (const float*)&qv;
#pragma unroll
                for (int ci = 0; ci < 4; ++ci) {
                    const int c = 4 * cc + ci;
                    ga = fmaf(w2a[c],  xs[ci], ga);
                    gb = fmaf(w2b[c],  xs[ci], gb);
                    ga = fmaf(w1pa[c], ps[ci], ga);
                    gb = fmaf(w1pb[c], ps[ci], gb);
                    ga = fmaf(w1ca[c], qs[ci], ga);
                    gb = fmaf(w1cb[c], qs[ci], gb);
                }
            }
        }
        *(float2*)&gbuf2[w][o0] = make_float2(ga, gb);
        asm volatile("s_waitcnt lgkmcnt(0)" ::: "memory");

        if (l < 32) {
            if (w == 7 && k < 15 && (t & 15) == 0 && t >= 48) {
                while (__hip_atomic_load(consprog, __ATOMIC_RELAXED,
                                         __HIP_MEMORY_SCOPE_AGENT) < t - 47) { }
            }
            const float go = gbuf2[w][l];
            const float gf = gbuf2[w][32 + l];
            const float gi = gbuf2[w][64 + l];
            const float gg = gbuf2[w][96 + l];
            const float so = 1.f / (1.f + __expf(-go));
            const float sf = 1.f / (1.f + __expf(-gf));
            const float si = 1.f / (1.f + __expf(-gi));
            const float tg = 2.f / (1.f + __expf(-2.f * gg)) - 1.f;
            const float nc = sf * pc + si * tg;
            const float th = 2.f / (1.f + __expf(-2.f * nc)) - 1.f;
            const float nh = so * th;
            pc = nc;
            phs[par ^ 1][w + 1][l] = nh;

            const int ph4 = t & 3;
            if (ph4 == 0) ob0 = nh;
            else if (ph4 == 1) ob1 = nh;
            else if (ph4 == 2) ob2 = nh;
            else *(float4*)(outrow + (t - 3)) = make_float4(ob0, ob1, ob2, nh);

            if (w == 7 && k < 15) {
                unsigned long long q = ((unsigned long long)(unsigned)(t + 1) << 32)
                                     | (unsigned long long)__float_as_uint(nh);
                __hip_atomic_store(&dstbase[(size_t)(t & (DEPTH - 1)) * BO], q,
                                   __ATOMIC_RELAXED, __HIP_MEMORY_SCOPE_AGENT);
            }
            if (w == 0 && l == 0) {
                __hip_atomic_store(myprog, t + 1, __ATOMIC_RELAXED,
                                   __HIP_MEMORY_SCOPE_AGENT);
            }
        }
        __syncthreads();
    }
}

extern "C" void kernel_launch(void* const* d_in, const int* in_sizes, int n_in,
                              void* d_out, int out_size, void* d_ws, size_t ws_size,
                              hipStream_t stream) {
    const float* x  = (const float*)d_in[0];
    const float* W2 = (const float*)d_in[1];
    const float* b2 = (const float*)d_in[2];
    const float* W1 = (const float*)d_in[3];
    const float* b1 = (const float*)d_in[4];
    float* out = (float*)d_out;

    int* progress = (int*)d_ws;
    unsigned long long* hand = (unsigned long long*)((char*)d_ws + 4096);
    _Float16* i2sh = (_Float16*)((char*)d_ws + 4096 + RINGMAX);

    const size_t need = 4096 + RINGMAX + I2SHSZ;

    if (ws_size >= need) {
        // v13 path: no ring state at all -> no memset needed (i2sh fully
        // rewritten by K1 each launch; deterministic under graph replay)
        hipLaunchKernelGGL(i2s_gemm_h, dim3(BATCH * HH), dim3(256), 0, stream,
                           x, W2, b2, b1, i2sh);
        hipLaunchKernelGGL(diag_lstm_scan_v13, dim3(BATCH), dim3(1024), 0, stream,
                           W1, out, i2sh);
    } else {
        hipMemsetAsync(d_ws, 0, 4096 + RINGMAX, stream);
        hipLaunchKernelGGL(diag_lstm_scan_v4, dim3(BATCH * 16), dim3(512), 0, stream,
                           x, W2, b2, W1, b1, out, progress, hand);
    }
}